// Round 6
// baseline (221.108 us; speedup 1.0000x reference)
//
#include <hip/hip_runtime.h>
#include <math.h>

// Problem constants
#define Bsz 32
#define Nn  4096
#define DU  64
#define Dm  128

#define GRID_MLP 768
#define BPB 24          // blocks per batch (768/32); 64 block-iters per batch, ragged 2-3 per block

// workspace layout (float offsets)
#define WS_WKQ 0      // [2][128]  Wk-slice @ q per head
#define WS_BKQ 256    // [2]       bk-slice . q
#define WS_CNT 288    // [32] int  per-batch completion counters   <- memset 0
#define WS_A   320    // [32][2]   sum of alpha                    <- memset 0
#define WS_S   384    // [32][2][128] sum alpha*z                  <- memset 0
#define WS_WP  8576   // packed bf16 MFMA B-fragments: 48 frags * 64 lanes * 8 ushort

#define H1STR 136     // shorts per h1 LDS row (128 + 8 pad), 16B-aligned

typedef short frag_ab __attribute__((ext_vector_type(8)));
typedef float frag_cd __attribute__((ext_vector_type(4)));

__device__ __forceinline__ unsigned short f2bf(float x) {   // RNE (precompute only)
    union { float f; unsigned int u; } c; c.f = x;
    unsigned int r = c.u + 0x7fffu + ((c.u >> 16) & 1u);
    return (unsigned short)(r >> 16);
}

// gelu(x) = x * sigmoid(2*y), y = c0*(x + c1*x^3); log2e folded: 7 VALU ops.
// k0 = -2*c0*log2e, k1 = k0*c1
__device__ __forceinline__ float gelu_fast(float x) {
    float t = x * x;
    float a = x * fmaf(t, -0.1029432f, -2.3022081f);
    float e = __builtin_amdgcn_exp2f(a);
    return x * __builtin_amdgcn_rcpf(1.0f + e);
}

// pack two fp32 -> two bf16 (RTZ; 35e-3 threshold has 2x margin over RNE's 7.8e-3)
__device__ __forceinline__ unsigned int pk_rtz(unsigned int alo, unsigned int bhi) {
    return (alo >> 16) | (bhi & 0xffff0000u);
}

// K0: 13 blocks. 0..11 pack W1/W2 into MFMA B-frag bf16 streams; 12 computes
// qv/wkq/bkq. (S/A/CNT zeroing via hipMemsetAsync in kernel_launch.)
__global__ __launch_bounds__(256) void precompute_kernel(
    const float* __restrict__ embed, const float* __restrict__ Wq,
    const float* __restrict__ bq, const float* __restrict__ Wk,
    const float* __restrict__ bk, const float* __restrict__ W1,
    const float* __restrict__ W2, float* __restrict__ ws)
{
    __shared__ float qv[128];
    const int tid = threadIdx.x;
    const int bid = blockIdx.x;

    if (bid < 12) {
        // B-frag layout: frag f, lane L (quad=L>>4, n=L&15) holds
        // B[ks*32 + quad*8 + j][nt*16 + n], j=0..7
        const int e = bid * 256 + tid;     // 0..3071
        const int f = e >> 6, L = e & 63;
        const int quad = L >> 4, n = L & 15;
        const float* src;
        int ks, nt;
        if (f < 16) { src = W1; ks = f >> 3;        nt = f & 7; }
        else        { src = W2; ks = (f - 16) >> 3; nt = (f - 16) & 7; }
        const int kb = ks * 32 + quad * 8;
        const int c  = nt * 16 + n;
        unsigned int p[4];
        #pragma unroll
        for (int jj = 0; jj < 4; ++jj) {
            unsigned int lo = f2bf(src[(kb + 2 * jj)     * Dm + c]);
            unsigned int hi = f2bf(src[(kb + 2 * jj + 1) * Dm + c]);
            p[jj] = lo | (hi << 16);
        }
        ((uint4*)(ws + WS_WP))[e] = make_uint4(p[0], p[1], p[2], p[3]);
    } else {
        if (tid < 128) {
            float s = bq[tid];
            #pragma unroll 8
            for (int j = 0; j < 128; ++j) s += embed[j] * Wq[j * 128 + tid];
            qv[tid] = s;
        }
        __syncthreads();
        if (tid < 128) {
            float s0 = 0.f, s1 = 0.f;
            #pragma unroll 8
            for (int dh = 0; dh < 64; ++dh) {
                s0 += Wk[tid * 128 + dh]      * qv[dh];
                s1 += Wk[tid * 128 + 64 + dh] * qv[64 + dh];
            }
            ws[WS_WKQ + tid]       = s0;
            ws[WS_WKQ + 128 + tid] = s1;
        }
        if (tid < 2) {
            float s = 0.f;
            for (int dh = 0; dh < 64; ++dh) s += bk[tid * 64 + dh] * qv[tid * 64 + dh];
            ws[WS_BKQ + tid] = s;
        }
    }
}

// K1: bf16-MFMA fused MLP + alpha + S/A pooling + per-batch fused epilogue.
// 768 blocks (3/CU) x 256 thr; ragged 2-3 block-iters, each 64 rows (4 waves x 16).
// LDS ~50 KB: w2 frags 32 KB (LDS beat global for w2 — R3 vs R5 A/B) + h1 17.4 KB.
// w1 frags (16 KB stream) from global L1. VGPR cap 168 via (256,3) -> 3 waves/SIMD.
__global__ __launch_bounds__(256, 3) void mlp_pool_kernel(
    const float* __restrict__ u,  const float* __restrict__ b1,
    const float* __restrict__ b2, const float* __restrict__ Wv,
    const float* __restrict__ bv, const float* __restrict__ Wo,
    const float* __restrict__ bo, float* __restrict__ ws,
    float* __restrict__ out)
{
    __shared__ short lds_w2[32 * 512];       // 32 KB layer-2 weight fragments
    __shared__ short lds_h1[4 * 16 * H1STR]; // per-wave 16 x 136 bf16 (reused by epilogue)
    __shared__ int   do_epi;

    const int tid  = threadIdx.x;
    const int wave = tid >> 6;
    const int lane = tid & 63;
    const int quad = lane >> 4;
    const int n15  = lane & 15;

    // stage layer-2 fragments (frags 16..47 of packed stream) global(L2) -> LDS
    {
        const float4* src = (const float4*)(ws + WS_WP) + 1024;
        float4* dst = (float4*)lds_w2;
        #pragma unroll
        for (int i = 0; i < 8; ++i) dst[tid + 256 * i] = src[tid + 256 * i];
    }
    // layer-1 fragments stay in global (16 KB stream, L1-resident)
    const frag_ab* w1g = (const frag_ab*)((const short*)(ws + WS_WP)) + lane;

    // persistent per-lane constants in registers
    float b1c[8], b2c[8], wkq0[8], wkq1[8];
    #pragma unroll
    for (int nt = 0; nt < 8; ++nt) {
        const int c = nt * 16 + n15;
        b1c[nt]  = b1[c];
        b2c[nt]  = b2[c];
        wkq0[nt] = ws[WS_WKQ + c];
        wkq1[nt] = ws[WS_WKQ + 128 + c];
    }
    const float bkq0 = ws[WS_BKQ];
    const float bkq1 = ws[WS_BKQ + 1];
    __syncthreads();

    const int bb  = blockIdx.x / BPB;            // batch
    const int jb  = blockIdx.x % BPB;
    const int it0 = (jb * 64) / BPB;             // ragged 2-3 iters per block
    const int it1 = ((jb + 1) * 64) / BPB;
    short* h1w = lds_h1 + wave * 16 * H1STR;

    float s0p[8], s1p[8];
    #pragma unroll
    for (int nt = 0; nt < 8; ++nt) { s0p[nt] = 0.f; s1p[nt] = 0.f; }
    float aA0 = 0.f, aA1 = 0.f;

    #pragma unroll 1            // keep rolled: full unroll spilled in R2
    for (int it = it0; it < it1; ++it) {
        // load 16 rows of u: lane (quad,n15) = row n15, k quad*8..+8 and +32
        const float* up = u + ((size_t)(bb * Nn + it * 64 + wave * 16 + n15)) * DU + quad * 8;
        uint4 g0 = *(const uint4*)(up);
        uint4 g1 = *(const uint4*)(up + 4);
        uint4 g2 = *(const uint4*)(up + 32);
        uint4 g3 = *(const uint4*)(up + 36);

        union { uint4 i; frag_ab f; } ua0, ua1;
        ua0.i.x = pk_rtz(g0.x, g0.y); ua0.i.y = pk_rtz(g0.z, g0.w);
        ua0.i.z = pk_rtz(g1.x, g1.y); ua0.i.w = pk_rtz(g1.z, g1.w);
        ua1.i.x = pk_rtz(g2.x, g2.y); ua1.i.y = pk_rtz(g2.z, g2.w);
        ua1.i.z = pk_rtz(g3.x, g3.y); ua1.i.w = pk_rtz(g3.z, g3.w);

        // ---- layer 1: h1 = gelu(u @ W1 + b1), M16 N128 K64  (B from global L1)
        frag_cd acc[8];
        #pragma unroll
        for (int nt = 0; nt < 8; ++nt) acc[nt] = (frag_cd){0.f, 0.f, 0.f, 0.f};
        #pragma unroll
        for (int nt = 0; nt < 8; ++nt) {
            frag_ab w0 = w1g[(nt)     * 64];
            acc[nt] = __builtin_amdgcn_mfma_f32_16x16x32_bf16(ua0.f, w0, acc[nt], 0, 0, 0);
            frag_ab w1 = w1g[(8 + nt) * 64];
            acc[nt] = __builtin_amdgcn_mfma_f32_16x16x32_bf16(ua1.f, w1, acc[nt], 0, 0, 0);
        }

        // bias + gelu (fp32) -> h1 bf16 (RTZ) in wave-private LDS [m][H1STR]
        // D layout: row = quad*4+reg, col = nt*16+n15
        #pragma unroll
        for (int nt = 0; nt < 8; ++nt) {
            #pragma unroll
            for (int r = 0; r < 4; ++r) {
                float g = gelu_fast(acc[nt][r] + b1c[nt]);
                h1w[(quad * 4 + r) * H1STR + nt * 16 + n15] =
                    (short)(__float_as_uint(g) >> 16);
            }
        }
        // no barrier: wave-private region, per-wave DS ordering

        // ---- layer 2: z = gelu(h1 @ W2 + b2), M16 N128 K128  (B from LDS)
        frag_cd acc2[8];
        #pragma unroll
        for (int nt = 0; nt < 8; ++nt) acc2[nt] = (frag_cd){0.f, 0.f, 0.f, 0.f};
        #pragma unroll
        for (int ks = 0; ks < 4; ++ks) {
            frag_ab a2 = *(const frag_ab*)&h1w[n15 * H1STR + ks * 32 + quad * 8];
            #pragma unroll
            for (int nt = 0; nt < 8; ++nt) {
                frag_ab w2f = *(const frag_ab*)&lds_w2[(ks * 8 + nt) * 512 + lane * 8];
                acc2[nt] = __builtin_amdgcn_mfma_f32_16x16x32_bf16(a2, w2f, acc2[nt], 0, 0, 0);
            }
        }

        // bias + gelu -> z fp32 in registers
        #pragma unroll
        for (int nt = 0; nt < 8; ++nt) {
            #pragma unroll
            for (int r = 0; r < 4; ++r)
                acc2[nt][r] = gelu_fast(acc2[nt][r] + b2c[nt]);
        }

        // ---- alpha[r][h] = z[r,:] . wkq[h] + bkq[h] (reduce over n15 lanes)
        float p0[4], p1[4];
        #pragma unroll
        for (int r = 0; r < 4; ++r) { p0[r] = 0.f; p1[r] = 0.f; }
        #pragma unroll
        for (int nt = 0; nt < 8; ++nt) {
            #pragma unroll
            for (int r = 0; r < 4; ++r) {
                p0[r] += acc2[nt][r] * wkq0[nt];
                p1[r] += acc2[nt][r] * wkq1[nt];
            }
        }
        #pragma unroll
        for (int r = 0; r < 4; ++r) {
            #pragma unroll
            for (int d = 1; d < 16; d <<= 1) {
                p0[r] += __shfl_xor(p0[r], d);
                p1[r] += __shfl_xor(p1[r], d);
            }
            p0[r] += bkq0;
            p1[r] += bkq1;
        }

        // ---- accumulate S and A
        #pragma unroll
        for (int nt = 0; nt < 8; ++nt) {
            #pragma unroll
            for (int r = 0; r < 4; ++r) {
                s0p[nt] += p0[r] * acc2[nt][r];
                s1p[nt] += p1[r] * acc2[nt][r];
            }
        }
        #pragma unroll
        for (int r = 0; r < 4; ++r) { aA0 += p0[r]; aA1 += p1[r]; }
    }

    // cross-quad reduce (quads hold disjoint rows), one atomic batch per wave
    #pragma unroll
    for (int nt = 0; nt < 8; ++nt) {
        s0p[nt] += __shfl_xor(s0p[nt], 16); s0p[nt] += __shfl_xor(s0p[nt], 32);
        s1p[nt] += __shfl_xor(s1p[nt], 16); s1p[nt] += __shfl_xor(s1p[nt], 32);
    }
    aA0 += __shfl_xor(aA0, 16); aA0 += __shfl_xor(aA0, 32);
    aA1 += __shfl_xor(aA1, 16); aA1 += __shfl_xor(aA1, 32);

    if (quad == 0) {
        #pragma unroll
        for (int nt = 0; nt < 8; ++nt) {
            const int c = nt * 16 + n15;
            atomicAdd(&ws[WS_S + (bb * 2 + 0) * 128 + c], s0p[nt]);
            atomicAdd(&ws[WS_S + (bb * 2 + 1) * 128 + c], s1p[nt]);
        }
    }
    if (lane == 0) {
        atomicAdd(&ws[WS_A + bb * 2 + 0], aA0);
        atomicAdd(&ws[WS_A + bb * 2 + 1], aA1);
    }

    // ---- per-batch completion counter; last (24th) finisher runs the epilogue
    __syncthreads();                 // all waves' atomics drained before counting
    if (tid == 0) {
        __threadfence();             // S/A atomics globally visible before counter inc
        int old = atomicAdd((int*)ws + WS_CNT + bb, 1);
        do_epi = (old == BPB - 1) ? 1 : 0;
    }
    __syncthreads();

    if (do_epi) {
        // reuse lds_h1 as float scratch: sS[256], sA[2], pooled[128], part[256]
        float* eb      = (float*)lds_h1;
        float* e_sS    = eb;
        float* e_sA    = eb + 256;
        float* e_pool  = eb + 264;
        float* e_part  = eb + 392;

        // device-coherent reads of accumulators (atomic RMW bypasses stale L1)
        e_sS[tid] = atomicAdd(&ws[WS_S + bb * 256 + tid], 0.f);
        if (tid < 2) e_sA[tid] = atomicAdd(&ws[WS_A + bb * 2 + tid], 0.f);
        __syncthreads();

        const int i = tid & 127, hf = tid >> 7;
        const int h = i >> 6;
        float dot = 0.f;
        #pragma unroll 8
        for (int d0 = 0; d0 < 64; ++d0) {
            const int d = hf * 64 + d0;
            dot += e_sS[h * 128 + d] * Wv[d * 128 + i];
        }
        e_part[tid] = dot;
        __syncthreads();
        if (tid < 128)
            e_pool[i] = (e_part[i] + e_part[128 + i] + e_sA[h] * bv[i]) * (1.0f / 4096.0f);
        __syncthreads();

        float o = 0.f;
        #pragma unroll 8
        for (int d0 = 0; d0 < 64; ++d0) {
            const int d = hf * 64 + d0;
            o += e_pool[d] * Wo[d * 128 + i];
        }
        e_part[tid] = o;
        __syncthreads();
        if (tid < 128)
            out[bb * 128 + i] = bo[i] + e_part[i] + e_part[128 + i];
    }
}

extern "C" void kernel_launch(void* const* d_in, const int* in_sizes, int n_in,
                              void* d_out, int out_size, void* d_ws, size_t ws_size,
                              hipStream_t stream) {
    const float* u     = (const float*)d_in[0];
    // d_in[1] = x : unused by the reference
    const float* W1    = (const float*)d_in[2];
    const float* b1    = (const float*)d_in[3];
    const float* W2    = (const float*)d_in[4];
    const float* b2    = (const float*)d_in[5];
    const float* embed = (const float*)d_in[6];
    const float* Wq    = (const float*)d_in[7];
    const float* bq    = (const float*)d_in[8];
    const float* Wk    = (const float*)d_in[9];
    const float* bk    = (const float*)d_in[10];
    const float* Wv    = (const float*)d_in[11];
    const float* bv    = (const float*)d_in[12];
    const float* Wo    = (const float*)d_in[13];
    const float* bo    = (const float*)d_in[14];
    float* ws  = (float*)d_ws;
    float* out = (float*)d_out;

    // zero CNT + A + S (floats 288..8575)
    hipMemsetAsync((char*)d_ws + WS_CNT * 4, 0, (WS_WP - WS_CNT) * 4, stream);
    hipLaunchKernelGGL(precompute_kernel, dim3(13), dim3(256), 0, stream,
                       embed, Wq, bq, Wk, bk, W1, W2, ws);
    hipLaunchKernelGGL(mlp_pool_kernel, dim3(GRID_MLP), dim3(256), 0, stream,
                       u, b1, b2, Wv, bv, Wo, bo, ws, out);
}

// Round 7
// 156.172 us; speedup vs baseline: 1.4158x; 1.4158x over previous
//
#include <hip/hip_runtime.h>
#include <math.h>

// Problem constants
#define Bsz 32
#define Nn  4096
#define DU  64
#define Dm  128

#define GRID_MLP 256    // 1 block/CU, 16 waves = 4 waves/SIMD (VGPR<=128 via block=1024)
#define BPB 8           // blocks per batch (256/32); 512 rows per block, 4 iters x 128 rows

// workspace layout (float offsets)
#define WS_WKQ 0      // [2][128]  Wk-slice @ q per head
#define WS_BKQ 256    // [2]       bk-slice . q
#define WS_CNT 288    // [32] int  per-batch completion counters   <- memset 0
#define WS_A   320    // [32][2]   sum of alpha                    <- memset 0
#define WS_S   384    // [32][2][128] sum alpha*z                  <- memset 0
#define WS_WP  8576   // packed bf16 MFMA B-fragments: 48 frags * 64 lanes * 8 ushort

#define H1STR 136     // shorts per h1 LDS row (128 + 8 pad), 16B-aligned

typedef short frag_ab __attribute__((ext_vector_type(8)));
typedef float frag_cd __attribute__((ext_vector_type(4)));

__device__ __forceinline__ unsigned short f2bf(float x) {   // RNE (R6's RTZ cost 4x absmax)
    union { float f; unsigned int u; } c; c.f = x;
    unsigned int r = c.u + 0x7fffu + ((c.u >> 16) & 1u);
    return (unsigned short)(r >> 16);
}

// gelu(x) = x * sigmoid(2y) (exact identity for tanh-gelu), log2e folded: ~5 VALU ops
__device__ __forceinline__ float gelu_fast(float x) {
    float t = x * x;
    float a = x * fmaf(t, -0.1029432f, -2.3022081f);
    float e = __builtin_amdgcn_exp2f(a);
    return x * __builtin_amdgcn_rcpf(1.0f + e);
}

// K0: 13 blocks. 0..11 pack W1/W2 into MFMA B-frag bf16 streams; 12 computes
// qv/wkq/bkq. (S/A/CNT zeroing via hipMemsetAsync in kernel_launch.)
__global__ __launch_bounds__(256) void precompute_kernel(
    const float* __restrict__ embed, const float* __restrict__ Wq,
    const float* __restrict__ bq, const float* __restrict__ Wk,
    const float* __restrict__ bk, const float* __restrict__ W1,
    const float* __restrict__ W2, float* __restrict__ ws)
{
    __shared__ float qv[128];
    const int tid = threadIdx.x;
    const int bid = blockIdx.x;

    if (bid < 12) {
        // B-frag layout: frag f, lane L (quad=L>>4, n=L&15) holds
        // B[ks*32 + quad*8 + j][nt*16 + n], j=0..7
        const int e = bid * 256 + tid;     // 0..3071
        const int f = e >> 6, L = e & 63;
        const int quad = L >> 4, n = L & 15;
        const float* src;
        int ks, nt;
        if (f < 16) { src = W1; ks = f >> 3;        nt = f & 7; }
        else        { src = W2; ks = (f - 16) >> 3; nt = (f - 16) & 7; }
        const int kb = ks * 32 + quad * 8;
        const int c  = nt * 16 + n;
        unsigned int p[4];
        #pragma unroll
        for (int jj = 0; jj < 4; ++jj) {
            unsigned int lo = f2bf(src[(kb + 2 * jj)     * Dm + c]);
            unsigned int hi = f2bf(src[(kb + 2 * jj + 1) * Dm + c]);
            p[jj] = lo | (hi << 16);
        }
        ((uint4*)(ws + WS_WP))[e] = make_uint4(p[0], p[1], p[2], p[3]);
    } else {
        if (tid < 128) {
            float s = bq[tid];
            #pragma unroll 8
            for (int j = 0; j < 128; ++j) s += embed[j] * Wq[j * 128 + tid];
            qv[tid] = s;
        }
        __syncthreads();
        if (tid < 128) {
            float s0 = 0.f, s1 = 0.f;
            #pragma unroll 8
            for (int dh = 0; dh < 64; ++dh) {
                s0 += Wk[tid * 128 + dh]      * qv[dh];
                s1 += Wk[tid * 128 + 64 + dh] * qv[64 + dh];
            }
            ws[WS_WKQ + tid]       = s0;
            ws[WS_WKQ + 128 + tid] = s1;
        }
        if (tid < 2) {
            float s = 0.f;
            for (int dh = 0; dh < 64; ++dh) s += bk[tid * 64 + dh] * qv[tid * 64 + dh];
            ws[WS_BKQ + tid] = s;
        }
    }
}

// K1: bf16-MFMA fused MLP + alpha + S/A pooling + per-batch fused epilogue.
// 256 blocks x 1024 thr (16 waves). Wave-pair N-split: pair p = wave>>1 owns a
// 16-row tile; half hf = wave&1 computes cols hf*64..+63 of each layer. Halves
// meet in the shared h1 tile (barrier) and a 2KB alpha buffer. Per-wave register
// demand ~95 -> fits the 128-VGPR budget block=1024 implies (4 waves/SIMD).
// NO second launch_bounds arg: it force-capped VGPRs and spilled in R3/R6.
__global__ __launch_bounds__(1024) void mlp_pool_kernel(
    const float* __restrict__ u,  const float* __restrict__ b1,
    const float* __restrict__ b2, const float* __restrict__ Wv,
    const float* __restrict__ bv, const float* __restrict__ Wo,
    const float* __restrict__ bo, float* __restrict__ ws,
    float* __restrict__ out)
{
    __shared__ short  lds_w[48 * 512];        // 48 KB weight fragments (both layers)
    __shared__ short  lds_h1[8 * 16 * H1STR]; // 8 pair-tiles x 16 x 136 bf16 (~34 KB)
    __shared__ float2 a2buf[8 * 16 * 2];      // [pair][row][h] -> (half0, half1)
    __shared__ int    do_epi;

    const int tid  = threadIdx.x;
    const int wave = tid >> 6;
    const int lane = tid & 63;
    const int quad = lane >> 4;
    const int n15  = lane & 15;
    const int p    = wave >> 1;     // tile pair 0..7
    const int hf   = wave & 1;      // column half

    // stage all weight fragments global(L2) -> LDS (48 KB, 3 float4/thread)
    {
        const float4* src = (const float4*)(ws + WS_WP);
        float4* dst = (float4*)lds_w;
        dst[tid]        = src[tid];
        dst[tid + 1024] = src[tid + 1024];
        dst[tid + 2048] = src[tid + 2048];
    }

    // per-lane constants for this wave's column half (20 VGPRs)
    float b1c[4], b2c[4], wkq0[4], wkq1[4];
    #pragma unroll
    for (int nt = 0; nt < 4; ++nt) {
        const int c = hf * 64 + nt * 16 + n15;
        b1c[nt]  = b1[c];
        b2c[nt]  = b2[c];
        wkq0[nt] = ws[WS_WKQ + c];
        wkq1[nt] = ws[WS_WKQ + 128 + c];
    }
    const float bkq0 = ws[WS_BKQ];
    const float bkq1 = ws[WS_BKQ + 1];
    __syncthreads();

    const int bb = blockIdx.x >> 3;          // batch
    const int jb = blockIdx.x & 7;           // 512-row chunk within batch
    short* h1t = lds_h1 + p * 16 * H1STR;    // pair-shared tile

    float s0p[4], s1p[4];
    #pragma unroll
    for (int nt = 0; nt < 4; ++nt) { s0p[nt] = 0.f; s1p[nt] = 0.f; }
    float aA0 = 0.f, aA1 = 0.f;

    #pragma unroll 1            // keep rolled (unroll spilled in R2)
    for (int it = 0; it < 4; ++it) {
        // both halves load the same 16 u rows (L3-hot; redundancy is cheap)
        const float* up = u + ((size_t)(bb * Nn + jb * 512 + it * 128 + p * 16 + n15)) * DU + quad * 8;
        float4 f0 = *(const float4*)(up);
        float4 f1 = *(const float4*)(up + 4);
        float4 f2 = *(const float4*)(up + 32);
        float4 f3 = *(const float4*)(up + 36);

        frag_ab a0, a1;
        a0[0] = (short)f2bf(f0.x); a0[1] = (short)f2bf(f0.y);
        a0[2] = (short)f2bf(f0.z); a0[3] = (short)f2bf(f0.w);
        a0[4] = (short)f2bf(f1.x); a0[5] = (short)f2bf(f1.y);
        a0[6] = (short)f2bf(f1.z); a0[7] = (short)f2bf(f1.w);
        a1[0] = (short)f2bf(f2.x); a1[1] = (short)f2bf(f2.y);
        a1[2] = (short)f2bf(f2.z); a1[3] = (short)f2bf(f2.w);
        a1[4] = (short)f2bf(f3.x); a1[5] = (short)f2bf(f3.y);
        a1[6] = (short)f2bf(f3.z); a1[7] = (short)f2bf(f3.w);

        // ---- layer 1 (this half's 64 cols): M16 N64 K64
        frag_cd acc[4];
        #pragma unroll
        for (int nt = 0; nt < 4; ++nt) acc[nt] = (frag_cd){0.f, 0.f, 0.f, 0.f};
        #pragma unroll
        for (int nt = 0; nt < 4; ++nt) {
            const int f = hf * 4 + nt;
            frag_ab w0 = *(const frag_ab*)&lds_w[(f)     * 512 + lane * 8];
            acc[nt] = __builtin_amdgcn_mfma_f32_16x16x32_bf16(a0, w0, acc[nt], 0, 0, 0);
            frag_ab w1 = *(const frag_ab*)&lds_w[(8 + f) * 512 + lane * 8];
            acc[nt] = __builtin_amdgcn_mfma_f32_16x16x32_bf16(a1, w1, acc[nt], 0, 0, 0);
        }

        // bias + gelu -> h1 bf16 (RNE) into the pair-shared tile
        // D layout: row = quad*4+r, col = hf*64 + nt*16 + n15
        #pragma unroll
        for (int nt = 0; nt < 4; ++nt) {
            #pragma unroll
            for (int r = 0; r < 4; ++r) {
                float g = gelu_fast(acc[nt][r] + b1c[nt]);
                h1t[(quad * 4 + r) * H1STR + hf * 64 + nt * 16 + n15] = (short)f2bf(g);
            }
        }
        __syncthreads();    // B1: both halves' h1 visible

        // ---- layer 2 (this half's 64 cols): M16 N64 K128, A from shared h1
        frag_cd acc2[4];
        #pragma unroll
        for (int nt = 0; nt < 4; ++nt) acc2[nt] = (frag_cd){0.f, 0.f, 0.f, 0.f};
        #pragma unroll
        for (int ks = 0; ks < 4; ++ks) {
            frag_ab a2 = *(const frag_ab*)&h1t[n15 * H1STR + ks * 32 + quad * 8];
            #pragma unroll
            for (int nt = 0; nt < 4; ++nt) {
                frag_ab w2f = *(const frag_ab*)&lds_w[(16 + ks * 8 + hf * 4 + nt) * 512 + lane * 8];
                acc2[nt] = __builtin_amdgcn_mfma_f32_16x16x32_bf16(a2, w2f, acc2[nt], 0, 0, 0);
            }
        }

        // bias + gelu -> z (this half) fp32 in registers
        #pragma unroll
        for (int nt = 0; nt < 4; ++nt) {
            #pragma unroll
            for (int r = 0; r < 4; ++r)
                acc2[nt][r] = gelu_fast(acc2[nt][r] + b2c[nt]);
        }

        // ---- half-alpha: sum over this half's 64 cols, reduce over n15 lanes
        float p0[4], p1[4];
        #pragma unroll
        for (int r = 0; r < 4; ++r) { p0[r] = 0.f; p1[r] = 0.f; }
        #pragma unroll
        for (int nt = 0; nt < 4; ++nt) {
            #pragma unroll
            for (int r = 0; r < 4; ++r) {
                p0[r] += acc2[nt][r] * wkq0[nt];
                p1[r] += acc2[nt][r] * wkq1[nt];
            }
        }
        #pragma unroll
        for (int r = 0; r < 4; ++r) {
            #pragma unroll
            for (int d = 1; d < 16; d <<= 1) {
                p0[r] += __shfl_xor(p0[r], d);
                p1[r] += __shfl_xor(p1[r], d);
            }
        }
        if (n15 == 0) {
            float* ab = (float*)a2buf;
            #pragma unroll
            for (int r = 0; r < 4; ++r) {
                const int row = quad * 4 + r;
                ab[(p * 32 + row * 2 + 0) * 2 + hf] = p0[r];
                ab[(p * 32 + row * 2 + 1) * 2 + hf] = p1[r];
            }
        }
        __syncthreads();    // B2: alpha halves visible (also protects h1 reuse)

        // ---- full alpha for my rows; accumulate S (my cols) and A
        #pragma unroll
        for (int r = 0; r < 4; ++r) {
            const int row = quad * 4 + r;
            float2 v0 = a2buf[p * 32 + row * 2 + 0];
            float2 v1 = a2buf[p * 32 + row * 2 + 1];
            const float al0 = v0.x + v0.y + bkq0;
            const float al1 = v1.x + v1.y + bkq1;
            #pragma unroll
            for (int nt = 0; nt < 4; ++nt) {
                s0p[nt] += al0 * acc2[nt][r];
                s1p[nt] += al1 * acc2[nt][r];
            }
            aA0 += al0; aA1 += al1;
        }
    }

    // cross-quad reduce (quads hold disjoint rows), one atomic batch per wave
    #pragma unroll
    for (int nt = 0; nt < 4; ++nt) {
        s0p[nt] += __shfl_xor(s0p[nt], 16); s0p[nt] += __shfl_xor(s0p[nt], 32);
        s1p[nt] += __shfl_xor(s1p[nt], 16); s1p[nt] += __shfl_xor(s1p[nt], 32);
    }
    aA0 += __shfl_xor(aA0, 16); aA0 += __shfl_xor(aA0, 32);
    aA1 += __shfl_xor(aA1, 16); aA1 += __shfl_xor(aA1, 32);

    if (quad == 0) {
        #pragma unroll
        for (int nt = 0; nt < 4; ++nt) {
            const int c = hf * 64 + nt * 16 + n15;
            atomicAdd(&ws[WS_S + (bb * 2 + 0) * 128 + c], s0p[nt]);
            atomicAdd(&ws[WS_S + (bb * 2 + 1) * 128 + c], s1p[nt]);
        }
    }
    if (hf == 0 && lane == 0) {     // both halves hold identical alpha sums; count once
        atomicAdd(&ws[WS_A + bb * 2 + 0], aA0);
        atomicAdd(&ws[WS_A + bb * 2 + 1], aA1);
    }

    // ---- per-batch completion counter; 8th finisher runs this batch's epilogue
    __syncthreads();
    if (tid == 0) {
        __threadfence();
        int old = atomicAdd((int*)ws + WS_CNT + bb, 1);
        do_epi = (old == BPB - 1) ? 1 : 0;
    }
    __syncthreads();

    if (do_epi) {
        // reuse lds_h1 as float scratch: sS[256], sA[2], pooled[128], part[512]
        float* eb     = (float*)lds_h1;
        float* e_sS   = eb;
        float* e_sA   = eb + 256;
        float* e_pool = eb + 264;
        float* e_part = eb + 392;

        if (tid < 256) e_sS[tid] = atomicAdd(&ws[WS_S + bb * 256 + tid], 0.f);
        if (tid < 2)   e_sA[tid] = atomicAdd(&ws[WS_A + bb * 2 + tid], 0.f);
        __syncthreads();

        const int i = tid & 127, seg = tid >> 7;      // 4-way split-K (tid<512)
        const int h = i >> 6;
        if (tid < 512) {
            float dot = 0.f;
            #pragma unroll 8
            for (int d0 = 0; d0 < 32; ++d0) {
                const int d = seg * 32 + d0;
                dot += e_sS[h * 128 + d] * Wv[d * 128 + i];
            }
            e_part[tid] = dot;
        }
        __syncthreads();
        if (tid < 128)
            e_pool[i] = (e_part[i] + e_part[128 + i] + e_part[256 + i] + e_part[384 + i]
                         + e_sA[h] * bv[i]) * (1.0f / 4096.0f);
        __syncthreads();

        if (tid < 512) {
            float o = 0.f;
            #pragma unroll 8
            for (int d0 = 0; d0 < 32; ++d0) {
                const int d = seg * 32 + d0;
                o += e_pool[d] * Wo[d * 128 + i];
            }
            e_part[tid] = o;
        }
        __syncthreads();
        if (tid < 128)
            out[bb * 128 + i] = bo[i] + e_part[i] + e_part[128 + i] + e_part[256 + i] + e_part[384 + i];
    }
}

extern "C" void kernel_launch(void* const* d_in, const int* in_sizes, int n_in,
                              void* d_out, int out_size, void* d_ws, size_t ws_size,
                              hipStream_t stream) {
    const float* u     = (const float*)d_in[0];
    // d_in[1] = x : unused by the reference
    const float* W1    = (const float*)d_in[2];
    const float* b1    = (const float*)d_in[3];
    const float* W2    = (const float*)d_in[4];
    const float* b2    = (const float*)d_in[5];
    const float* embed = (const float*)d_in[6];
    const float* Wq    = (const float*)d_in[7];
    const float* bq    = (const float*)d_in[8];
    const float* Wk    = (const float*)d_in[9];
    const float* bk    = (const float*)d_in[10];
    const float* Wv    = (const float*)d_in[11];
    const float* bv    = (const float*)d_in[12];
    const float* Wo    = (const float*)d_in[13];
    const float* bo    = (const float*)d_in[14];
    float* ws  = (float*)d_ws;
    float* out = (float*)d_out;

    // zero CNT + A + S (floats 288..8575)
    hipMemsetAsync((char*)d_ws + WS_CNT * 4, 0, (WS_WP - WS_CNT) * 4, stream);
    hipLaunchKernelGGL(precompute_kernel, dim3(13), dim3(256), 0, stream,
                       embed, Wq, bq, Wk, bk, W1, W2, ws);
    hipLaunchKernelGGL(mlp_pool_kernel, dim3(GRID_MLP), dim3(1024), 0, stream,
                       u, b1, b2, Wv, bv, Wo, bo, ws, out);
}

// Round 8
// 155.491 us; speedup vs baseline: 1.4220x; 1.0044x over previous
//
#include <hip/hip_runtime.h>
#include <math.h>

// Problem constants
#define Bsz 32
#define Nn  4096
#define DU  64
#define Dm  128

#define GRID_MLP 256    // 1 block/CU, 16 waves = 4 waves/SIMD
#define BPB 8           // blocks per batch; 512 rows per block, 4 iters x 128 rows

// workspace layout (float offsets) — only cross-block accumulators remain
#define WS_CNT 288    // [32] int  per-batch completion counters   <- memset 0
#define WS_A   320    // [32][2]   sum of alpha                    <- memset 0
#define WS_S   384    // [32][2][128] sum alpha*z                  <- memset 0
#define WS_END 8576

#define H1STR 136     // shorts per h1 LDS row (128 + 8 pad), 16B-aligned

typedef short frag_ab __attribute__((ext_vector_type(8)));
typedef float frag_cd __attribute__((ext_vector_type(4)));

__device__ __forceinline__ unsigned short f2bf(float x) {   // RNE (R6's RTZ cost 4x absmax)
    union { float f; unsigned int u; } c; c.f = x;
    unsigned int r = c.u + 0x7fffu + ((c.u >> 16) & 1u);
    return (unsigned short)(r >> 16);
}

// gelu(x) = x * sigmoid(2y) (exact identity for tanh-gelu), log2e folded
__device__ __forceinline__ float gelu_fast(float x) {
    float t = x * x;
    float a = x * fmaf(t, -0.1029432f, -2.3022081f);
    float e = __builtin_amdgcn_exp2f(a);
    return x * __builtin_amdgcn_rcpf(1.0f + e);
}

// Single fused kernel: per-block weight packing + qv/wkq setup, bf16-MFMA MLP,
// alpha + S/A pooling (software-pipelined, ONE barrier per iter), per-batch
// fused epilogue. 256 blocks x 1024 thr (16 waves; wave-pair N-split as R7).
// NO second launch_bounds arg (R3/R6: it force-caps VGPRs and spills); block=1024
// alone makes the compiler keep VGPR <= 128 (4 waves/SIMD).
__global__ __launch_bounds__(1024) void fused_mlp_pool_kernel(
    const float* __restrict__ u,   const float* __restrict__ W1,
    const float* __restrict__ b1,  const float* __restrict__ W2,
    const float* __restrict__ b2,  const float* __restrict__ embed,
    const float* __restrict__ Wq,  const float* __restrict__ bq,
    const float* __restrict__ Wk,  const float* __restrict__ bk,
    const float* __restrict__ Wv,  const float* __restrict__ bv,
    const float* __restrict__ Wo,  const float* __restrict__ bo,
    float* __restrict__ ws, float* __restrict__ out)
{
    __shared__ short lds_w[48 * 512];            // 48 KB weight fragments (both layers)
    __shared__ short lds_h1[2][8 * 16 * H1STR];  // double-buffered pair tiles (68 KB)
    __shared__ float a2buf[2][8][16][2][2];      // [buf][pair][row][head][half] (4 KB)
    __shared__ float lds_c[258];                 // wkq[256], bkq[2]
    __shared__ int   do_epi;

    const int tid  = threadIdx.x;
    const int wave = tid >> 6;
    const int lane = tid & 63;
    const int quad = lane >> 4;
    const int n15  = lane & 15;
    const int p    = wave >> 1;     // tile pair 0..7
    const int hf   = wave & 1;      // column half

    // ======== fused setup (was precompute_kernel) ========
    // phase A: waves 0-1 compute qv; waves 2-15 pack W1/W2 -> MFMA B-frags in LDS
    float* qtmp = (float*)a2buf;    // scratch reuse; a2buf first written in iter 0
    if (tid < 128) {
        float s = bq[tid];
        #pragma unroll 8
        for (int j = 0; j < 128; ++j) s += embed[j] * Wq[j * 128 + tid];
        qtmp[tid] = s;
    } else {
        // frag f, lane L (q2=L>>4, n=L&15) holds B[ks*32+q2*8+j][nt*16+n], j=0..7
        for (int e = tid - 128; e < 3072; e += 896) {
            const int f = e >> 6, L = e & 63;
            const int q2 = L >> 4, n = L & 15;
            const float* src;
            int ks, nt;
            if (f < 16) { src = W1; ks = f >> 3;        nt = f & 7; }
            else        { src = W2; ks = (f - 16) >> 3; nt = (f - 16) & 7; }
            const int kb = ks * 32 + q2 * 8;
            const int c  = nt * 16 + n;
            unsigned int pk[4];
            #pragma unroll
            for (int jj = 0; jj < 4; ++jj) {
                unsigned int lo = f2bf(src[(kb + 2 * jj)     * Dm + c]);
                unsigned int hi = f2bf(src[(kb + 2 * jj + 1) * Dm + c]);
                pk[jj] = lo | (hi << 16);
            }
            ((uint4*)lds_w)[e] = make_uint4(pk[0], pk[1], pk[2], pk[3]);
        }
    }
    __syncthreads();
    // phase B: wkq/bkq from qv
    if (tid < 128) {
        float s0 = 0.f, s1 = 0.f;
        #pragma unroll 8
        for (int dh = 0; dh < 64; ++dh) {
            s0 += Wk[tid * 128 + dh]      * qtmp[dh];
            s1 += Wk[tid * 128 + 64 + dh] * qtmp[64 + dh];
        }
        lds_c[tid]       = s0;
        lds_c[128 + tid] = s1;
    }
    if (tid < 2) {
        float s = 0.f;
        for (int dh = 0; dh < 64; ++dh) s += bk[tid * 64 + dh] * qtmp[tid * 64 + dh];
        lds_c[256 + tid] = s;
    }
    __syncthreads();

    // per-lane constants for this wave's column half
    float b1c[4], b2c[4], wkq0[4], wkq1[4];
    #pragma unroll
    for (int nt = 0; nt < 4; ++nt) {
        const int c = hf * 64 + nt * 16 + n15;
        b1c[nt]  = b1[c];
        b2c[nt]  = b2[c];
        wkq0[nt] = lds_c[c];
        wkq1[nt] = lds_c[128 + c];
    }
    const float bkq0 = lds_c[256];
    const float bkq1 = lds_c[257];

    // ======== main pipelined loop ========
    const int bb = blockIdx.x >> 3;          // batch
    const int jb = blockIdx.x & 7;           // 512-row chunk within batch

    float s0p[4], s1p[4];
    #pragma unroll
    for (int nt = 0; nt < 4; ++nt) { s0p[nt] = 0.f; s1p[nt] = 0.f; }
    float aA0 = 0.f, aA1 = 0.f;
    frag_cd zprev[4];
    int cur = 0;

    // prefetch u for iter 0: lane (quad,n15) = row n15 of pair tile, k quad*8..+8, +32
    const float* ub = u + ((size_t)(bb * Nn + jb * 512 + p * 16 + n15)) * DU + quad * 8;
    float4 f0 = *(const float4*)(ub);
    float4 f1 = *(const float4*)(ub + 4);
    float4 f2 = *(const float4*)(ub + 32);
    float4 f3 = *(const float4*)(ub + 36);

    #pragma unroll 1            // keep rolled (full unroll spilled in R2)
    for (int it = 0; it < 4; ++it) {
        frag_ab a0, a1;
        a0[0] = (short)f2bf(f0.x); a0[1] = (short)f2bf(f0.y);
        a0[2] = (short)f2bf(f0.z); a0[3] = (short)f2bf(f0.w);
        a0[4] = (short)f2bf(f1.x); a0[5] = (short)f2bf(f1.y);
        a0[6] = (short)f2bf(f1.z); a0[7] = (short)f2bf(f1.w);
        a1[0] = (short)f2bf(f2.x); a1[1] = (short)f2bf(f2.y);
        a1[2] = (short)f2bf(f2.z); a1[3] = (short)f2bf(f2.w);
        a1[4] = (short)f2bf(f3.x); a1[5] = (short)f2bf(f3.y);
        a1[6] = (short)f2bf(f3.z); a1[7] = (short)f2bf(f3.w);

        // prefetch next iter's u (in flight across both MFMA layers)
        if (it < 3) {
            const float* un = ub + (size_t)((it + 1) * 128) * DU;
            f0 = *(const float4*)(un);
            f1 = *(const float4*)(un + 4);
            f2 = *(const float4*)(un + 32);
            f3 = *(const float4*)(un + 36);
        }

        // ---- layer 1 (this half's 64 cols): M16 N64 K64
        frag_cd acc[4];
        #pragma unroll
        for (int nt = 0; nt < 4; ++nt) acc[nt] = (frag_cd){0.f, 0.f, 0.f, 0.f};
        #pragma unroll
        for (int nt = 0; nt < 4; ++nt) {
            const int f = hf * 4 + nt;
            frag_ab w0 = *(const frag_ab*)&lds_w[(f)     * 512 + lane * 8];
            acc[nt] = __builtin_amdgcn_mfma_f32_16x16x32_bf16(a0, w0, acc[nt], 0, 0, 0);
            frag_ab w1 = *(const frag_ab*)&lds_w[(8 + f) * 512 + lane * 8];
            acc[nt] = __builtin_amdgcn_mfma_f32_16x16x32_bf16(a1, w1, acc[nt], 0, 0, 0);
        }

        // bias + gelu -> h1 bf16 (RNE) into double-buffered pair tile
        short* h1t = lds_h1[cur] + p * 16 * H1STR;
        #pragma unroll
        for (int nt = 0; nt < 4; ++nt) {
            #pragma unroll
            for (int r = 0; r < 4; ++r) {
                float g = gelu_fast(acc[nt][r] + b1c[nt]);
                h1t[(quad * 4 + r) * H1STR + hf * 64 + nt * 16 + n15] = (short)f2bf(g);
            }
        }
        __syncthreads();    // the ONE barrier: h1[cur] and a2buf[1-cur] both complete

        // ---- consume previous iter's alpha against zprev (pipelined exchange)
        if (it > 0) {
            const int pb = 1 - cur;
            #pragma unroll
            for (int r = 0; r < 4; ++r) {
                const int row = quad * 4 + r;
                const float al0 = a2buf[pb][p][row][0][0] + a2buf[pb][p][row][0][1] + bkq0;
                const float al1 = a2buf[pb][p][row][1][0] + a2buf[pb][p][row][1][1] + bkq1;
                #pragma unroll
                for (int nt = 0; nt < 4; ++nt) {
                    s0p[nt] += al0 * zprev[nt][r];
                    s1p[nt] += al1 * zprev[nt][r];
                }
                aA0 += al0; aA1 += al1;
            }
        }

        // ---- layer 2 (this half's 64 cols): M16 N64 K128, A from shared h1[cur]
        frag_cd acc2[4];
        #pragma unroll
        for (int nt = 0; nt < 4; ++nt) acc2[nt] = (frag_cd){0.f, 0.f, 0.f, 0.f};
        #pragma unroll
        for (int ks = 0; ks < 4; ++ks) {
            frag_ab a2 = *(const frag_ab*)&h1t[n15 * H1STR + ks * 32 + quad * 8];
            #pragma unroll
            for (int nt = 0; nt < 4; ++nt) {
                frag_ab w2f = *(const frag_ab*)&lds_w[(16 + ks * 8 + hf * 4 + nt) * 512 + lane * 8];
                acc2[nt] = __builtin_amdgcn_mfma_f32_16x16x32_bf16(a2, w2f, acc2[nt], 0, 0, 0);
            }
        }

        // bias + gelu -> z (this half) fp32 in registers
        #pragma unroll
        for (int nt = 0; nt < 4; ++nt) {
            #pragma unroll
            for (int r = 0; r < 4; ++r)
                acc2[nt][r] = gelu_fast(acc2[nt][r] + b2c[nt]);
        }

        // ---- half-alpha dots, reduce over n15 lanes, publish to a2buf[cur]
        float p0[4], p1[4];
        #pragma unroll
        for (int r = 0; r < 4; ++r) { p0[r] = 0.f; p1[r] = 0.f; }
        #pragma unroll
        for (int nt = 0; nt < 4; ++nt) {
            #pragma unroll
            for (int r = 0; r < 4; ++r) {
                p0[r] += acc2[nt][r] * wkq0[nt];
                p1[r] += acc2[nt][r] * wkq1[nt];
            }
        }
        #pragma unroll
        for (int r = 0; r < 4; ++r) {
            #pragma unroll
            for (int d = 1; d < 16; d <<= 1) {
                p0[r] += __shfl_xor(p0[r], d);
                p1[r] += __shfl_xor(p1[r], d);
            }
        }
        if (n15 == 0) {
            #pragma unroll
            for (int r = 0; r < 4; ++r) {
                const int row = quad * 4 + r;
                a2buf[cur][p][row][0][hf] = p0[r];
                a2buf[cur][p][row][1][hf] = p1[r];
            }
        }
        #pragma unroll
        for (int nt = 0; nt < 4; ++nt) zprev[nt] = acc2[nt];
        cur ^= 1;
    }

    __syncthreads();    // last a2buf writes visible
    {   // drain: consume iter-3's alpha (buffer 1-cur)
        const int pb = 1 - cur;
        #pragma unroll
        for (int r = 0; r < 4; ++r) {
            const int row = quad * 4 + r;
            const float al0 = a2buf[pb][p][row][0][0] + a2buf[pb][p][row][0][1] + bkq0;
            const float al1 = a2buf[pb][p][row][1][0] + a2buf[pb][p][row][1][1] + bkq1;
            #pragma unroll
            for (int nt = 0; nt < 4; ++nt) {
                s0p[nt] += al0 * zprev[nt][r];
                s1p[nt] += al1 * zprev[nt][r];
            }
            aA0 += al0; aA1 += al1;
        }
    }

    // cross-quad reduce (quads hold disjoint rows), one atomic batch per wave
    #pragma unroll
    for (int nt = 0; nt < 4; ++nt) {
        s0p[nt] += __shfl_xor(s0p[nt], 16); s0p[nt] += __shfl_xor(s0p[nt], 32);
        s1p[nt] += __shfl_xor(s1p[nt], 16); s1p[nt] += __shfl_xor(s1p[nt], 32);
    }
    aA0 += __shfl_xor(aA0, 16); aA0 += __shfl_xor(aA0, 32);
    aA1 += __shfl_xor(aA1, 16); aA1 += __shfl_xor(aA1, 32);

    if (quad == 0) {
        #pragma unroll
        for (int nt = 0; nt < 4; ++nt) {
            const int c = hf * 64 + nt * 16 + n15;
            atomicAdd(&ws[WS_S + (bb * 2 + 0) * 128 + c], s0p[nt]);
            atomicAdd(&ws[WS_S + (bb * 2 + 1) * 128 + c], s1p[nt]);
        }
    }
    if (hf == 0 && lane == 0) {     // both halves hold identical alpha sums; count once
        atomicAdd(&ws[WS_A + bb * 2 + 0], aA0);
        atomicAdd(&ws[WS_A + bb * 2 + 1], aA1);
    }

    // ---- per-batch completion counter; 8th finisher runs this batch's epilogue
    __syncthreads();
    if (tid == 0) {
        __threadfence();
        int old = atomicAdd((int*)ws + WS_CNT + bb, 1);
        do_epi = (old == BPB - 1) ? 1 : 0;
    }
    __syncthreads();

    if (do_epi) {
        // reuse lds_h1 as float scratch: sS[256], sA[2], pooled[128], part[512]
        float* eb     = (float*)lds_h1;
        float* e_sS   = eb;
        float* e_sA   = eb + 256;
        float* e_pool = eb + 264;
        float* e_part = eb + 392;

        if (tid < 256) e_sS[tid] = atomicAdd(&ws[WS_S + bb * 256 + tid], 0.f);
        if (tid < 2)   e_sA[tid] = atomicAdd(&ws[WS_A + bb * 2 + tid], 0.f);
        __syncthreads();

        const int i = tid & 127, seg = tid >> 7;      // 4-way split-K (tid<512)
        const int h = i >> 6;
        if (tid < 512) {
            float dot = 0.f;
            #pragma unroll 8
            for (int d0 = 0; d0 < 32; ++d0) {
                const int d = seg * 32 + d0;
                dot += e_sS[h * 128 + d] * Wv[d * 128 + i];
            }
            e_part[tid] = dot;
        }
        __syncthreads();
        if (tid < 128)
            e_pool[i] = (e_part[i] + e_part[128 + i] + e_part[256 + i] + e_part[384 + i]
                         + e_sA[h] * bv[i]) * (1.0f / 4096.0f);
        __syncthreads();

        if (tid < 512) {
            float o = 0.f;
            #pragma unroll 8
            for (int d0 = 0; d0 < 32; ++d0) {
                const int d = seg * 32 + d0;
                o += e_pool[d] * Wo[d * 128 + i];
            }
            e_part[tid] = o;
        }
        __syncthreads();
        if (tid < 128)
            out[bb * 128 + i] = bo[i] + e_part[i] + e_part[128 + i] + e_part[256 + i] + e_part[384 + i];
    }
}

extern "C" void kernel_launch(void* const* d_in, const int* in_sizes, int n_in,
                              void* d_out, int out_size, void* d_ws, size_t ws_size,
                              hipStream_t stream) {
    const float* u     = (const float*)d_in[0];
    // d_in[1] = x : unused by the reference
    const float* W1    = (const float*)d_in[2];
    const float* b1    = (const float*)d_in[3];
    const float* W2    = (const float*)d_in[4];
    const float* b2    = (const float*)d_in[5];
    const float* embed = (const float*)d_in[6];
    const float* Wq    = (const float*)d_in[7];
    const float* bq    = (const float*)d_in[8];
    const float* Wk    = (const float*)d_in[9];
    const float* bk    = (const float*)d_in[10];
    const float* Wv    = (const float*)d_in[11];
    const float* bv    = (const float*)d_in[12];
    const float* Wo    = (const float*)d_in[13];
    const float* bo    = (const float*)d_in[14];
    float* ws  = (float*)d_ws;
    float* out = (float*)d_out;

    // zero CNT + A + S
    hipMemsetAsync((char*)d_ws + WS_CNT * 4, 0, (WS_END - WS_CNT) * 4, stream);
    hipLaunchKernelGGL(fused_mlp_pool_kernel, dim3(GRID_MLP), dim3(1024), 0, stream,
                       u, W1, b1, W2, b2, embed, Wq, bq, Wk, bk, Wv, bv, Wo, bo, ws, out);
}